// Round 4
// baseline (451.589 us; speedup 1.0000x reference)
//
#include <hip/hip_runtime.h>

typedef __bf16 bf16x8 __attribute__((ext_vector_type(8)));
typedef float f32x4 __attribute__((ext_vector_type(4)));

// workspace layout (bf16 elements):
//   [0)      Weff   [112][128]  (unit, k)  pre-scaled by 2*log2e, col100 = 2*log2e*b_enc
//   [14336)  whh_p  [3][112][128]          r,z pre-scaled by log2e (col100 = log2e*(b_ih+b_hh));
//                                          n pre-scaled by 2*log2e (col100 = 2*log2e*b_hh_n)
//   [57344)  w1_p   [64][128]  (yunit, k)  col100 = b1
#define WS_WENC 0
#define WS_WHH  14336
#define WS_W1   57344
#define LOG2E 1.4426950408889634f

__device__ __forceinline__ float fast_exp2(float x) {
#if __has_builtin(__builtin_amdgcn_exp2f)
  return __builtin_amdgcn_exp2f(x);
#else
  return exp2f(x);
#endif
}
__device__ __forceinline__ float fast_rcp(float x) {
#if __has_builtin(__builtin_amdgcn_rcpf)
  return __builtin_amdgcn_rcpf(x);
#else
  return 1.f / x;
#endif
}

__global__ void prep_kernel(const float* __restrict__ w_enc,
                            const float* __restrict__ b_enc,
                            const float* __restrict__ w_hh,
                            const float* __restrict__ b_ih,
                            const float* __restrict__ b_hh,
                            const float* __restrict__ w1,
                            const float* __restrict__ b1,
                            __bf16* __restrict__ ws) {
  int idx = blockIdx.x * 256 + threadIdx.x;
  if (idx < 14336) {
    // Weff[i][n] = w_enc[i][n] + sum_k w_enc[i][100+k]*cos(2pi k n/100) - w_enc[i][151+k]*sin(2pi k n/100)
    int i = idx >> 7, n = idx & 127;
    float acc = 0.f;
    if (i < 100) {
      if (n < 100) {
        const float* wr = w_enc + i * 202;
        acc = wr[n];
        #pragma unroll 1
        for (int k = 0; k <= 50; ++k) {
          int m = (k * n) % 100;                 // exact range reduction
          float th = 0.062831853071795864f * (float)m;
          float s, c;
          __sincosf(th, &s, &c);
          acc += wr[100 + k] * c - wr[151 + k] * s;
        }
        acc *= 2.f * LOG2E;
      } else if (n == 100) {
        acc = 2.f * LOG2E * b_enc[i];
      }
    }
    ws[idx] = (__bf16)acc;
  } else if (idx < 57344) {
    int j = idx - 14336;
    int g = j / 14336;
    int rem = j - g * 14336;
    int u2 = rem >> 7, c2 = rem & 127;
    float scale = (g == 2) ? 2.f * LOG2E : LOG2E;
    float v = 0.f;
    if (u2 < 100) {
      if (c2 < 100) v = scale * w_hh[(g * 100 + u2) * 100 + c2];
      else if (c2 == 100) {
        v = (g == 2) ? scale * b_hh[200 + u2]
                     : scale * (b_ih[g * 100 + u2] + b_hh[g * 100 + u2]);
      }
    }
    ws[idx] = (__bf16)v;
  } else if (idx < 65536) {
    int j = idx - 57344;
    int r2 = j >> 7, c2 = j & 127;
    float v = 0.f;
    if (r2 < 50) {
      if (c2 < 100) v = w1[r2 * 100 + c2];
      else if (c2 == 100) v = b1[r2];
    }
    ws[idx] = (__bf16)v;
  }
}

__device__ __forceinline__ f32x4 mfma16(bf16x8 a, bf16x8 b, f32x4 c) {
  return __builtin_amdgcn_mfma_f32_16x16x32_bf16(a, b, c, 0, 0, 0);
}
// input already scaled by log2e:  sigm = rcp(1 + 2^-a)
__device__ __forceinline__ float sigm2(float a) { return fast_rcp(1.f + fast_exp2(-a)); }
// input already scaled by 2*log2e: tanh = 2*rcp(1 + 2^-b) - 1
__device__ __forceinline__ float tanh2(float b) { return fmaf(2.f, fast_rcp(1.f + fast_exp2(-b)), -1.f); }

// block = 448 threads = 7 waves, 32 sequences per block (two 16-seq MFMA groups).
// wave w owns hidden units [16w, 16w+16) for BOTH groups (w_hh frags resident in VGPRs).
// y-matmul is REPLICATED in every wave (transposed: w1 tile as A, h as B); xv is
// assembled fully in-register (2 shfl_xor + per-r shfl), so each step needs only
// ONE __syncthreads (double-buffered h).
// MFMA 16x16x32_bf16; C/D layout: col = lane&15, row = 4*(lane>>4)+reg (HW-verified).
// Bias trick: h column 100 pinned to 1.0; weight column 100 carries the biases.
// All LDS tiles use stride 136 elements (272 B) -> 2-way bank aliasing only.
__global__ __launch_bounds__(448, 4)
void gru_main(const float* __restrict__ enc,
              const float* __restrict__ w_ih,
              const float* __restrict__ b_ih,
              const float* __restrict__ w2,
              const float* __restrict__ b2,
              const __bf16* __restrict__ ws,
              float* __restrict__ out) {
  __shared__ __align__(16) __bf16 hbuf[2][32 * 136];  // [buf][seq 0..31][unit]
  __shared__ __align__(16) __bf16 wYl[64 * 136];      // w1_p, restrided 128->136
  __shared__ float w2l[64];

  const int tid = threadIdx.x;
  const int w = tid >> 6;
  const int l = tid & 63;
  const int c = l & 15;        // tile column / seq-in-group
  const int grp = l >> 4;      // 0..3
  const int klo = 8 * grp;     // within-K-tile offset
  const int seqbase = blockIdx.x * 32;
  const int u = 16 * w + c;    // this lane's hidden unit
  const bool vu = (u < 100);
  const float padf = (u == 100) ? 1.f : 0.f;  // constant-1 bias column at unit 100

  // init LDS h-buffers: pad cols zero except col 100 = 1.0
  for (int i = tid; i < 2 * 32 * 136; i += 448)
    hbuf[0][i] = (__bf16)((i % 136 == 100) ? 1.f : 0.f);
  // stage w1_p into LDS with stride restrip 128 -> 136 (1024 16B chunks)
  for (int i = tid; i < 1024; i += 448) {
    int row = i >> 4, off = (i & 15) * 8;
    *(bf16x8*)&wYl[row * 136 + off] = *(const bf16x8*)(ws + WS_W1 + row * 128 + off);
  }
  if (tid < 64) w2l[tid] = (tid < 50) ? w2[tid] : 0.f;

  // per-lane constants (pre-scaled)
  float wihr = 0.f, wihz = 0.f, wihn = 0.f, bin_ = 0.f;
  if (vu) {
    wihr = w_ih[u] * LOG2E;
    wihz = w_ih[100 + u] * LOG2E;
    wihn = w_ih[200 + u] * (2.f * LOG2E);
    bin_ = b_ih[200 + u] * (2.f * LOG2E);
  }
  const float b2v = b2[0];

  // resident w_hh fragments (shared across both seq groups)
  bf16x8 wR[3][4];
  #pragma unroll
  for (int g = 0; g < 3; ++g) {
    #pragma unroll
    for (int kt = 0; kt < 4; ++kt)
      wR[g][kt] = *(const bf16x8*)(ws + WS_WHH + (g * 112 + u) * 128 + kt * 32 + klo);
  }

  // ---------- encoder: h0 = tanh(sig @ Weff^T), DFT + bias folded into Weff ----------
  float h_old[2][4];
  {
    #pragma unroll
    for (int g = 0; g < 2; ++g) {
      f32x4 hc = {0.f, 0.f, 0.f, 0.f};
      const float* srow = enc + (size_t)(seqbase + 16 * g + c) * 100;
      #pragma unroll
      for (int kt = 0; kt < 4; ++kt) {
        bf16x8 wE = *(const bf16x8*)(ws + WS_WENC + u * 128 + kt * 32 + klo);
        int t0 = kt * 32 + klo;
        float f0 = 0.f, f1 = 0.f, f2 = 0.f, f3 = 0.f, f4 = 0.f, f5 = 0.f, f6 = 0.f, f7 = 0.f;
        if (t0 + 8 <= 100) {
          float4 va = *(const float4*)(srow + t0);
          float4 vb = *(const float4*)(srow + t0 + 4);
          f0 = va.x; f1 = va.y; f2 = va.z; f3 = va.w;
          f4 = vb.x; f5 = vb.y; f6 = vb.z; f7 = vb.w;
        } else if (t0 < 100) {  // t0 == 96: 4 real + slot 100 = 1.0 (bias)
          float4 va = *(const float4*)(srow + t0);
          f0 = va.x; f1 = va.y; f2 = va.z; f3 = va.w;
          f4 = 1.f;
        }
        bf16x8 a;
        a[0] = (__bf16)f0; a[1] = (__bf16)f1; a[2] = (__bf16)f2; a[3] = (__bf16)f3;
        a[4] = (__bf16)f4; a[5] = (__bf16)f5; a[6] = (__bf16)f6; a[7] = (__bf16)f7;
        hc = mfma16(a, wE, hc);
      }
      #pragma unroll
      for (int r = 0; r < 4; ++r) h_old[g][r] = vu ? tanh2(hc[r]) : 0.f;
    }
  }
  // x at t=0 is the last encoder input sample
  float x0[2][4];
  #pragma unroll
  for (int g = 0; g < 2; ++g)
    #pragma unroll
    for (int r = 0; r < 4; ++r)
      x0[g][r] = enc[(size_t)(seqbase + 16 * g + 4 * grp + r) * 100 + 99];

  __syncthreads();  // LDS init + wYl/w2l staging complete
  #pragma unroll
  for (int g = 0; g < 2; ++g)
    #pragma unroll
    for (int r = 0; r < 4; ++r)
      hbuf[0][(16 * g + 4 * grp + r) * 136 + u] = (__bf16)(vu ? h_old[g][r] : padf);
  __syncthreads();

  // ---------- decoder: t=0..50; interval t computes y_{t-1} (t>0) and h_{t+1} (t<50) ----------
  // ONE barrier per step.
  #pragma unroll 1
  for (int t = 0; t <= 50; ++t) {
    const int rb = t & 1;
    // h_t fragments for both groups (serve gate MFMAs as A and y MFMAs as B)
    bf16x8 a0[4], a1[4];
    #pragma unroll
    for (int kt = 0; kt < 4; ++kt) {
      a0[kt] = *(const bf16x8*)&hbuf[rb][c * 136 + kt * 32 + klo];
      a1[kt] = *(const bf16x8*)&hbuf[rb][(16 + c) * 136 + kt * 32 + klo];
    }

    // ---- replicated y-phase: every wave computes full y for both groups ----
    float p0 = 0.f, p1 = 0.f;
    if (t > 0) {
      #pragma unroll
      for (int tile = 0; tile < 4; ++tile) {
        f32x4 Cy0 = {0.f, 0.f, 0.f, 0.f}, Cy1 = {0.f, 0.f, 0.f, 0.f};
        #pragma unroll
        for (int kt = 0; kt < 4; ++kt) {
          bf16x8 wyf = *(const bf16x8*)&wYl[(tile * 16 + c) * 136 + kt * 32 + klo];
          Cy0 = mfma16(wyf, a0[kt], Cy0);
          Cy1 = mfma16(wyf, a1[kt], Cy1);
        }
        #pragma unroll
        for (int r = 0; r < 4; ++r) {
          float wv = w2l[tile * 16 + 4 * grp + r];   // broadcast read
          float v0 = Cy0[r]; v0 = fmaxf(v0, 0.01f * v0);
          float v1 = Cy1[r]; v1 = fmaxf(v1, 0.01f * v1);
          p0 = fmaf(wv, v0, p0);
          p1 = fmaf(wv, v1, p1);
        }
      }
      // cross-grp reduce: p now full y-sum for seq = lane&15, uniform in grp
      p0 += __shfl_xor(p0, 16); p0 += __shfl_xor(p0, 32);
      p1 += __shfl_xor(p1, 16); p1 += __shfl_xor(p1, 32);
      if (w == 6 && l < 32) {
        float val = ((l < 16) ? p0 : p1) + b2v;
        out[(size_t)(seqbase + l) * 50 + (t - 1)] = val;
      }
    }

    // ---- gates + elementwise, serialized per group (register pressure) ----
    if (t < 50) {
      const int wb = rb ^ 1;
      {  // group 0
        f32x4 Cr = {0.f,0.f,0.f,0.f}, Cz = {0.f,0.f,0.f,0.f}, Cn = {0.f,0.f,0.f,0.f};
        #pragma unroll
        for (int kt = 0; kt < 4; ++kt) {
          Cr = mfma16(a0[kt], wR[0][kt], Cr);
          Cz = mfma16(a0[kt], wR[1][kt], Cz);
          Cn = mfma16(a0[kt], wR[2][kt], Cn);
        }
        #pragma unroll
        for (int r = 0; r < 4; ++r) {
          float xv = (t > 0) ? (__shfl(p0, 4 * grp + r, 16) + b2v) : x0[0][r];
          float ar = fmaf(xv, wihr, Cr[r]);
          float rg = sigm2(ar);
          float az = fmaf(xv, wihz, Cz[r]);
          float zg = sigm2(az);
          float bn = fmaf(rg, Cn[r], fmaf(xv, wihn, bin_));
          float ng = tanh2(bn);
          float hn = fmaf(zg, h_old[0][r] - ng, ng);
          h_old[0][r] = hn;
          hbuf[wb][(4 * grp + r) * 136 + u] = (__bf16)(vu ? hn : padf);
        }
      }
      {  // group 1
        f32x4 Cr = {0.f,0.f,0.f,0.f}, Cz = {0.f,0.f,0.f,0.f}, Cn = {0.f,0.f,0.f,0.f};
        #pragma unroll
        for (int kt = 0; kt < 4; ++kt) {
          Cr = mfma16(a1[kt], wR[0][kt], Cr);
          Cz = mfma16(a1[kt], wR[1][kt], Cz);
          Cn = mfma16(a1[kt], wR[2][kt], Cn);
        }
        #pragma unroll
        for (int r = 0; r < 4; ++r) {
          float xv = (t > 0) ? (__shfl(p1, 4 * grp + r, 16) + b2v) : x0[1][r];
          float ar = fmaf(xv, wihr, Cr[r]);
          float rg = sigm2(ar);
          float az = fmaf(xv, wihz, Cz[r]);
          float zg = sigm2(az);
          float bn = fmaf(rg, Cn[r], fmaf(xv, wihn, bin_));
          float ng = tanh2(bn);
          float hn = fmaf(zg, h_old[1][r] - ng, ng);
          h_old[1][r] = hn;
          hbuf[wb][(16 + 4 * grp + r) * 136 + u] = (__bf16)(vu ? hn : padf);
        }
      }
    }
    __syncthreads();
  }
}

extern "C" void kernel_launch(void* const* d_in, const int* in_sizes, int n_in,
                              void* d_out, int out_size, void* d_ws, size_t ws_size,
                              hipStream_t stream) {
  const float* enc   = (const float*)d_in[0];
  const float* w_enc = (const float*)d_in[1];
  const float* b_enc = (const float*)d_in[2];
  const float* w_ih  = (const float*)d_in[3];
  const float* b_ih  = (const float*)d_in[4];
  const float* w_hh  = (const float*)d_in[5];
  const float* b_hh  = (const float*)d_in[6];
  const float* w1    = (const float*)d_in[7];
  const float* b1    = (const float*)d_in[8];
  const float* w2    = (const float*)d_in[9];
  const float* b2    = (const float*)d_in[10];
  __bf16* ws = (__bf16*)d_ws;
  float* out = (float*)d_out;

  prep_kernel<<<256, 256, 0, stream>>>(w_enc, b_enc, w_hh, b_ih, b_hh, w1, b1, ws);
  gru_main<<<32768 / 32, 448, 0, stream>>>(enc, w_ih, b_ih, w2, b2, ws, out);
}